// Round 5
// baseline (424.510 us; speedup 1.0000x reference)
//
#include <hip/hip_runtime.h>
#include <hip/hip_bf16.h>
#include <math.h>

#define NB 8192
#define NN 20
#define DD 128
#define HH 8
#define FFD 512
#define NROWS (NB * NN)          // 163840 total rows

typedef __attribute__((ext_vector_type(8))) short bf16x8;
typedef __attribute__((ext_vector_type(4))) float f32x4;

__device__ __forceinline__ unsigned short f2bf(float f) {
  union { __hip_bfloat16 h; unsigned short u; } cv; cv.h = __float2bfloat16(f); return cv.u;
}
__device__ __forceinline__ float bf2f(unsigned short u) {
  union { unsigned short u; __hip_bfloat16 h; } cv; cv.u = u; return __bfloat162float(cv.h);
}
__device__ __forceinline__ float gelu_t(float v) {
  float u = v * (0.7978845608f + 0.0356774081f * v * v);
  float e = __expf(2.f * u);
  float th = 1.f - 2.f / (e + 1.f);
  return 0.5f * v * (1.f + th);
}

// ======================= prep: weight frag swizzle + bias fuse =======================
__global__ __launch_bounds__(256) void prep2(
    const float* __restrict__ wq, const float* __restrict__ wk, const float* __restrict__ wv,
    const float* __restrict__ w1, const float* __restrict__ w2, const float* __restrict__ wo,
    const float* __restrict__ rel, const float* __restrict__ gb, const float* __restrict__ alpha,
    unsigned short* __restrict__ WcF, unsigned short* __restrict__ w1F,
    unsigned short* __restrict__ w2F, unsigned short* __restrict__ woF,
    float* __restrict__ biasT)
{
  int bid = blockIdx.x, t = threadIdx.x;
  if (bid < 288) {            // conv: per-projection frag planes [p][nt8][kc12][64][8]
    int nt = bid / 12, kc = bid % 12;
    for (int i = t; i < 512; i += 256) {
      int lane = i >> 3, j = i & 7;
      int k = kc * 32 + (lane >> 4) * 8 + j;
      int c = nt * 16 + (lane & 15);
      int kk = k >> 7, din = k & 127;
      int which = c >> 7, dout = c & 127;
      const float* w = (which == 0) ? wq : (which == 1) ? wk : wv;
      WcF[((nt * 12 + kc) * 64 + lane) * 8 + j] = f2bf(w[(dout * 128 + din) * 3 + kk]);
    }
  } else if (bid < 416) {     // w1: K=128 (kc 4), N=512 (nt 32)
    int tt = bid - 288; int nt = tt / 4, kc = tt % 4;
    for (int i = t; i < 512; i += 256) {
      int lane = i >> 3, j = i & 7;
      int k = kc * 32 + (lane >> 4) * 8 + j;
      int c = nt * 16 + (lane & 15);
      w1F[((nt * 4 + kc) * 64 + lane) * 8 + j] = f2bf(w1[k * 512 + c]);
    }
  } else if (bid < 544) {     // w2: K=512 (kc 16), N=128 (nt 8)
    int tt = bid - 416; int nt = tt / 16, kc = tt % 16;
    for (int i = t; i < 512; i += 256) {
      int lane = i >> 3, j = i & 7;
      int k = kc * 32 + (lane >> 4) * 8 + j;
      int c = nt * 16 + (lane & 15);
      w2F[((nt * 16 + kc) * 64 + lane) * 8 + j] = f2bf(w2[k * 128 + c]);
    }
  } else if (bid < 576) {     // wo: K=128 (kc 4), N=128 (nt 8)
    int tt = bid - 544; int nt = tt / 4, kc = tt % 4;
    for (int i = t; i < 512; i += 256) {
      int lane = i >> 3, j = i & 7;
      int k = kc * 32 + (lane >> 4) * 8 + j;
      int c = nt * 16 + (lane & 15);
      woF[((nt * 4 + kc) * 64 + lane) * 8 + j] = f2bf(wo[k * 128 + c]);
    }
  } else {                    // bias fuse
    int h = bid - 576; float a = alpha[0];
    for (int i = t; i < 400; i += 256) {
      int n = i / 20, m = i % 20;
      biasT[h * 400 + i] = rel[(n - m + 19) * 8 + h] + gb[h * 400 + i] * a;
    }
  }
}

// ======================= conv1d-QKV (R4, kept): per-projection 128x128 tile, LDS-resident B ======
__global__ __launch_bounds__(256, 3) void conv_qkv(
    const float* __restrict__ x, const unsigned short* __restrict__ WcF,
    const float* __restrict__ lnq_w, const float* __restrict__ lnq_b,
    const float* __restrict__ lnk_w, const float* __restrict__ lnk_b,
    const float* __restrict__ lnv_w, const float* __restrict__ lnv_b,
    unsigned short* __restrict__ qP, unsigned short* __restrict__ kP,
    unsigned short* __restrict__ vP)
{
  __shared__ __align__(16) unsigned short xA[130 * 136];      // 35360 B (rows g0-1..g0+128)
  __shared__ __align__(16) unsigned short Bb[2][8 * 64 * 8];  // 2 x 8192 B

  const int t = threadIdx.x;
  const int w = t >> 6, l = t & 63;
  const int l15 = l & 15, l4 = l >> 4;
  const int p = blockIdx.y;
  const long g0 = (long)blockIdx.x * 128;
  const unsigned short* Wp = WcF + (size_t)p * 8 * 12 * 512;  // [nt8][kc12][64][8]

  for (int i = t; i < 130 * 32; i += 256) {
    int r = i >> 5, c4 = i & 31;
    long g = g0 - 1 + r;
    long gc = g < 0 ? 0 : (g >= NROWS ? NROWS - 1 : g);
    float4 v = *(const float4*)(x + gc * 128 + c4 * 4);
    ushort4 pk; pk.x = f2bf(v.x); pk.y = f2bf(v.y); pk.z = f2bf(v.z); pk.w = f2bf(v.w);
    *(ushort4*)&xA[r * 136 + c4 * 4] = pk;
  }

  const int snt = t >> 5, sinner = t & 31;
  const unsigned short* sB = Wp + snt * 12 * 512 + sinner * 16;
  unsigned short* dB0 = &Bb[0][snt * 512 + sinner * 16];
  unsigned short* dB1 = &Bb[1][snt * 512 + sinner * 16];

  bf16x8 h0, h1;
  {
    bf16x8 a = *(const bf16x8*)(sB);
    bf16x8 b = *(const bf16x8*)(sB + 8);
    *(bf16x8*)dB0 = a; *(bf16x8*)(dB0 + 8) = b;
    h0 = *(const bf16x8*)(sB + 512);
    h1 = *(const bf16x8*)(sB + 512 + 8);
  }
  __syncthreads();

  const int rA0 = w * 32 + l15;
  const int rA1 = rA0 + 16;
  const int nA0 = (int)((g0 + rA0) % 20);
  const int nA1 = (int)((g0 + rA1) % 20);

  f32x4 acc[2][8];
  #pragma unroll
  for (int mt = 0; mt < 2; ++mt)
    #pragma unroll
    for (int nt = 0; nt < 8; ++nt) acc[mt][nt] = (f32x4){0.f, 0.f, 0.f, 0.f};

  const bf16x8 zz = {};
  for (int kc = 0; kc < 12; ++kc) {
    const int kk = kc >> 2, k4 = kc & 3;
    const bool m0 = (kk == 1) || ((kk == 0) ? (nA0 != 0) : (nA0 != 19));
    const bool m1 = (kk == 1) || ((kk == 0) ? (nA1 != 0) : (nA1 != 19));
    bf16x8 a0 = *(const bf16x8*)&xA[(rA0 + kk) * 136 + k4 * 32 + l4 * 8]; if (!m0) a0 = zz;
    bf16x8 a1 = *(const bf16x8*)&xA[(rA1 + kk) * 136 + k4 * 32 + l4 * 8]; if (!m1) a1 = zz;
    const unsigned short* bb = &Bb[kc & 1][l * 8];
    #pragma unroll
    for (int nt = 0; nt < 8; ++nt) {
      bf16x8 b = *(const bf16x8*)(bb + nt * 512);
      acc[0][nt] = __builtin_amdgcn_mfma_f32_16x16x32_bf16(a0, b, acc[0][nt], 0, 0, 0);
      acc[1][nt] = __builtin_amdgcn_mfma_f32_16x16x32_bf16(a1, b, acc[1][nt], 0, 0, 0);
    }
    if (kc < 11) {
      unsigned short* d = (kc & 1) ? dB0 : dB1;
      *(bf16x8*)d = h0; *(bf16x8*)(d + 8) = h1;
    }
    if (kc < 10) {
      h0 = *(const bf16x8*)(sB + (kc + 2) * 512);
      h1 = *(const bf16x8*)(sB + (kc + 2) * 512 + 8);
    }
    __syncthreads();
  }

  const float* lw = (p == 0) ? lnq_w : (p == 1) ? lnk_w : lnv_w;
  const float* lb = (p == 0) ? lnq_b : (p == 1) ? lnk_b : lnv_b;
  float gw8[8], gb8[8];
  #pragma unroll
  for (int nt = 0; nt < 8; ++nt) { gw8[nt] = lw[nt * 16 + l15]; gb8[nt] = lb[nt * 16 + l15]; }

  #pragma unroll
  for (int mt = 0; mt < 2; ++mt) {
    float s[4], qq[4];
    #pragma unroll
    for (int j = 0; j < 4; ++j) {
      float a0 = 0.f, a1 = 0.f;
      #pragma unroll
      for (int nt = 0; nt < 8; ++nt) { float v = acc[mt][nt][j]; a0 += v; a1 = fmaf(v, v, a1); }
      s[j] = a0; qq[j] = a1;
    }
    #pragma unroll
    for (int off = 1; off < 16; off <<= 1) {
      #pragma unroll
      for (int j = 0; j < 4; ++j) { s[j] += __shfl_xor(s[j], off); qq[j] += __shfl_xor(qq[j], off); }
    }
    #pragma unroll
    for (int j = 0; j < 4; ++j) {
      float mean = s[j] * (1.f / 128.f);
      float var  = qq[j] * (1.f / 128.f) - mean * mean;
      float inv  = rsqrtf(var + 1e-5f);
      int lr = w * 32 + mt * 16 + l4 * 4 + j;
      #pragma unroll
      for (int nt = 0; nt < 8; ++nt)
        xA[lr * 136 + nt * 16 + l15] = f2bf((acc[mt][nt][j] - mean) * inv * gw8[nt] + gb8[nt]);
    }
  }
  __syncthreads();

  unsigned short* plane = (p == 0) ? qP : (p == 1) ? kP : vP;
  const float qs = (p == 0) ? 0.25f : 1.0f;
  for (int i = t; i < 128 * 16; i += 256) {
    int r = i >> 4, c8 = i & 15;
    bf16x8 ob = *(const bf16x8*)&xA[r * 136 + c8 * 8];
    long grow = g0 + r;
    const float* xr8 = x + grow * 128 + c8 * 8;
    float4 xa = *(const float4*)xr8;
    float4 xb = *(const float4*)(xr8 + 4);
    bf16x8 o;
    o[0] = (short)f2bf((xa.x + bf2f((unsigned short)ob[0])) * qs);
    o[1] = (short)f2bf((xa.y + bf2f((unsigned short)ob[1])) * qs);
    o[2] = (short)f2bf((xa.z + bf2f((unsigned short)ob[2])) * qs);
    o[3] = (short)f2bf((xa.w + bf2f((unsigned short)ob[3])) * qs);
    o[4] = (short)f2bf((xb.x + bf2f((unsigned short)ob[4])) * qs);
    o[5] = (short)f2bf((xb.y + bf2f((unsigned short)ob[5])) * qs);
    o[6] = (short)f2bf((xb.z + bf2f((unsigned short)ob[6])) * qs);
    o[7] = (short)f2bf((xb.w + bf2f((unsigned short)ob[7])) * qs);
    *(bf16x8*)&plane[grow * 128 + c8 * 8] = o;
  }
}

// ======================= attn_wo v2: 320 thr (5 waves), 1 attention row per thread ==============
// 2 elements/block. LDS 47104B -> 3 blocks/CU (15 waves/CU).
//   ks [2][20][136] bf16 @0      (10880)   (ctx aliases after QK)
//   vs [2][20][136] bf16 @10880  (10880)
//   scr [48][132]  f32   @21760  (25344)
__global__ __launch_bounds__(320) void attn_wo(
    const float* __restrict__ x,
    const unsigned short* __restrict__ qP, const unsigned short* __restrict__ kP,
    const unsigned short* __restrict__ vP,
    const unsigned short* __restrict__ woF, const float* __restrict__ biasT,
    const float* __restrict__ bo,
    const float* __restrict__ n1w, const float* __restrict__ n1b,
    unsigned short* __restrict__ xr)
{
  __shared__ __align__(16) char smem[47104];
  unsigned short* ks  = (unsigned short*)smem;
  unsigned short* vs  = (unsigned short*)(smem + 10880);
  unsigned short* ctx = ks;
  float* scr = (float*)(smem + 21760);

  const int t = threadIdx.x;
  const int w = t >> 6, l = t & 63;
  const int l15 = l & 15, l4 = l >> 4;
  const int eb = blockIdx.x * 2;
  const float* xg = x + (size_t)eb * (NN * DD);

  // ---- stage k,v ----
  for (int i = t; i < 1280; i += 320) {
    int proj = i / 640, r = i % 640;
    int e = r / 320, rr = r % 320;
    int n = rr / 16, c8 = rr % 16;
    const unsigned short* src = (proj == 0 ? kP : vP) + (((size_t)(eb + e) * 20 + n) * 128 + c8 * 8);
    unsigned short* dst = (proj == 0 ? ks : vs) + ((e * 20 + n) * 136 + c8 * 8);
    *(bf16x8*)dst = *(const bf16x8*)src;
  }
  __syncthreads();

  // ---- QK + softmax: thread t owns row t (320 rows exactly) ----
  float pm[20];
  {
    int e = t / 160, hh = (t / 20) % 8, n = t % 20;
    const unsigned short* qr = qP + ((size_t)(eb + e) * 20 + n) * 128 + hh * 16;
    bf16x8 qa = *(const bf16x8*)qr, qb = *(const bf16x8*)(qr + 8);
    float q[16];
    #pragma unroll
    for (int j = 0; j < 8; ++j) { q[j] = bf2f((unsigned short)qa[j]); q[8 + j] = bf2f((unsigned short)qb[j]); }
    float bias[20];
    const float* bp = &biasT[(hh * 20 + n) * 20];
    #pragma unroll
    for (int m4 = 0; m4 < 5; ++m4) {
      float4 bv = *(const float4*)(bp + m4 * 4);
      bias[m4 * 4] = bv.x; bias[m4 * 4 + 1] = bv.y; bias[m4 * 4 + 2] = bv.z; bias[m4 * 4 + 3] = bv.w;
    }
    float mx = -1e30f;
    #pragma unroll
    for (int m = 0; m < 20; ++m) {
      const unsigned short* kr = &ks[(e * 20 + m) * 136 + hh * 16];
      bf16x8 ka = *(const bf16x8*)kr, kb = *(const bf16x8*)(kr + 8);
      float sv = bias[m];
      #pragma unroll
      for (int j = 0; j < 8; ++j) {
        sv = fmaf(q[j], bf2f((unsigned short)ka[j]), sv);
        sv = fmaf(q[8 + j], bf2f((unsigned short)kb[j]), sv);
      }
      pm[m] = sv; mx = fmaxf(mx, sv);
    }
    float sum = 0.f;
    #pragma unroll
    for (int m = 0; m < 20; ++m) { pm[m] = __expf(pm[m] - mx); sum += pm[m]; }
    float rs = 1.f / sum;
    #pragma unroll
    for (int m = 0; m < 20; ++m) pm[m] *= rs;
  }
  __syncthreads();   // ks fully consumed

  // ---- PV -> ctx (aliases ks) ----
  {
    int e = t / 160, hh = (t / 20) % 8, n = t % 20;
    float c[16];
    #pragma unroll
    for (int j = 0; j < 16; ++j) c[j] = 0.f;
    #pragma unroll
    for (int m = 0; m < 20; ++m) {
      const unsigned short* vr = &vs[(e * 20 + m) * 136 + hh * 16];
      bf16x8 va = *(const bf16x8*)vr, vb = *(const bf16x8*)(vr + 8);
      float pv = pm[m];
      #pragma unroll
      for (int j = 0; j < 8; ++j) {
        c[j] = fmaf(pv, bf2f((unsigned short)va[j]), c[j]);
        c[8 + j] = fmaf(pv, bf2f((unsigned short)vb[j]), c[8 + j]);
      }
    }
    bf16x8 c0, c1;
    #pragma unroll
    for (int j = 0; j < 8; ++j) { c0[j] = (short)f2bf(c[j]); c1[j] = (short)f2bf(c[8 + j]); }
    *(bf16x8*)&ctx[(e * 20 + n) * 136 + hh * 16] = c0;
    *(bf16x8*)&ctx[(e * 20 + n) * 136 + hh * 16 + 8] = c1;
  }
  __syncthreads();

  // ---- wo GEMM (waves 0-3) ----
  if (w < 4) {
    int emap[3], nmap[3];
    #pragma unroll
    for (int mt = 0; mt < 3; ++mt) {
      int g = mt * 16 + l15;
      int e = g / 20, n = g - e * 20;
      if (e > 1) { e = 1; n = 19; }
      emap[mt] = e; nmap[mt] = n;
    }
    f32x4 acc[3][2];
    #pragma unroll
    for (int mt = 0; mt < 3; ++mt)
      #pragma unroll
      for (int i = 0; i < 2; ++i) acc[mt][i] = (f32x4){0.f, 0.f, 0.f, 0.f};
    #pragma unroll
    for (int kc = 0; kc < 4; ++kc) {
      bf16x8 a[3], b[2];
      #pragma unroll
      for (int mt = 0; mt < 3; ++mt)
        a[mt] = *(const bf16x8*)&ctx[(emap[mt] * 20 + nmap[mt]) * 136 + kc * 32 + l4 * 8];
      #pragma unroll
      for (int i = 0; i < 2; ++i) {
        int ntg = w * 2 + i;
        b[i] = *(const bf16x8*)&woF[((ntg * 4 + kc) * 64 + l) * 8];
      }
      #pragma unroll
      for (int mt = 0; mt < 3; ++mt)
        #pragma unroll
        for (int i = 0; i < 2; ++i)
          acc[mt][i] = __builtin_amdgcn_mfma_f32_16x16x32_bf16(a[mt], b[i], acc[mt][i], 0, 0, 0);
    }
    #pragma unroll
    for (int mt = 0; mt < 3; ++mt)
      #pragma unroll
      for (int i = 0; i < 2; ++i) {
        int col = (w * 2 + i) * 16 + l15;
        int rbase = mt * 16 + l4 * 4;
        #pragma unroll
        for (int j = 0; j < 4; ++j) scr[(rbase + j) * 132 + col] = acc[mt][i][j];
      }
  }
  __syncthreads();

  // ---- LN1(x + attn_out + bo) -> xr bf16 (5 waves, 8 rows each) ----
  for (int r = w; r < 40; r += 5) {
    int e = r / 20, n = r % 20;
    float v0 = scr[r * 132 + l]      + bo[l]      + xg[e * 2560 + n * 128 + l];
    float v1 = scr[r * 132 + 64 + l] + bo[64 + l] + xg[e * 2560 + n * 128 + 64 + l];
    float s = v0 + v1, sq = v0 * v0 + v1 * v1;
    #pragma unroll
    for (int off = 32; off > 0; off >>= 1) { s += __shfl_xor(s, off); sq += __shfl_xor(sq, off); }
    float mean = s * (1.f / 128.f);
    float var  = sq * (1.f / 128.f) - mean * mean;
    float inv  = rsqrtf(var + 1e-5f);
    size_t ro = ((size_t)(eb + e) * 20 + n) * 128;
    xr[ro + l]      = f2bf((v0 - mean) * inv * n1w[l] + n1b[l]);
    xr[ro + 64 + l] = f2bf((v1 - mean) * inv * n1w[64 + l] + n1b[64 + l]);
  }
}

// ======================= FFN + LN2 (R3 v1, known-good ~25us): 32 rows/block =======================
__global__ __launch_bounds__(256, 3) void ffn_c(
    const unsigned short* __restrict__ xr,
    const unsigned short* __restrict__ w1F, const unsigned short* __restrict__ w2F,
    const float* __restrict__ b1, const float* __restrict__ b2,
    const float* __restrict__ n2w, const float* __restrict__ n2b,
    float* __restrict__ out)
{
  __shared__ __align__(16) char smem[8704 + 33280];
  unsigned short* xrb = (unsigned short*)smem;
  unsigned short* h   = (unsigned short*)(smem + 8704);
  float* sc2          = (float*)(smem + 8704);

  const int t = threadIdx.x;
  const int w = t >> 6, l = t & 63;
  const int l15 = l & 15, l4 = l >> 4;
  const size_t row0 = (size_t)blockIdx.x * 32;

  for (int i = t; i < 512; i += 256) {
    int r = i >> 4, c8 = i & 15;
    *(bf16x8*)&xrb[r * 136 + c8 * 8] = *(const bf16x8*)&xr[(row0 + r) * 128 + c8 * 8];
  }
  __syncthreads();

  {
    f32x4 acc[2][8];
    #pragma unroll
    for (int mt = 0; mt < 2; ++mt)
      #pragma unroll
      for (int i = 0; i < 8; ++i) acc[mt][i] = (f32x4){0.f, 0.f, 0.f, 0.f};
    for (int kc = 0; kc < 4; ++kc) {
      bf16x8 a[2];
      #pragma unroll
      for (int mt = 0; mt < 2; ++mt)
        a[mt] = *(const bf16x8*)&xrb[(mt * 16 + l15) * 136 + kc * 32 + l4 * 8];
      #pragma unroll
      for (int i = 0; i < 8; ++i) {
        int ntg = w * 8 + i;
        bf16x8 b = *(const bf16x8*)&w1F[((ntg * 4 + kc) * 64 + l) * 8];
        #pragma unroll
        for (int mt = 0; mt < 2; ++mt)
          acc[mt][i] = __builtin_amdgcn_mfma_f32_16x16x32_bf16(a[mt], b, acc[mt][i], 0, 0, 0);
      }
    }
    #pragma unroll
    for (int i = 0; i < 8; ++i) {
      int col = (w * 8 + i) * 16 + l15;
      float b1v = b1[col];
      #pragma unroll
      for (int mt = 0; mt < 2; ++mt)
        #pragma unroll
        for (int j = 0; j < 4; ++j) {
          float v = acc[mt][i][j] + b1v;
          h[(mt * 16 + l4 * 4 + j) * 520 + col] = f2bf(gelu_t(v));
        }
    }
  }
  __syncthreads();

  f32x4 acc2[2][2];
  #pragma unroll
  for (int mt = 0; mt < 2; ++mt)
    #pragma unroll
    for (int i = 0; i < 2; ++i) acc2[mt][i] = (f32x4){0.f, 0.f, 0.f, 0.f};
  for (int kc = 0; kc < 16; ++kc) {
    bf16x8 a[2];
    #pragma unroll
    for (int mt = 0; mt < 2; ++mt)
      a[mt] = *(const bf16x8*)&h[(mt * 16 + l15) * 520 + kc * 32 + l4 * 8];
    #pragma unroll
    for (int i = 0; i < 2; ++i) {
      int ntg = w * 2 + i;
      bf16x8 b = *(const bf16x8*)&w2F[((ntg * 16 + kc) * 64 + l) * 8];
      #pragma unroll
      for (int mt = 0; mt < 2; ++mt)
        acc2[mt][i] = __builtin_amdgcn_mfma_f32_16x16x32_bf16(a[mt], b, acc2[mt][i], 0, 0, 0);
    }
  }
  __syncthreads();

  #pragma unroll
  for (int mt = 0; mt < 2; ++mt)
    #pragma unroll
    for (int i = 0; i < 2; ++i) {
      int col = (w * 2 + i) * 16 + l15;
      int rbase = mt * 16 + l4 * 4;
      #pragma unroll
      for (int j = 0; j < 4; ++j) sc2[(rbase + j) * 132 + col] = acc2[mt][i][j];
    }
  __syncthreads();

  for (int r = w; r < 32; r += 4) {
    float v0 = sc2[r * 132 + l]      + b2[l]      + bf2f(xrb[r * 136 + l]);
    float v1 = sc2[r * 132 + 64 + l] + b2[64 + l] + bf2f(xrb[r * 136 + 64 + l]);
    float s = v0 + v1, sq = v0 * v0 + v1 * v1;
    #pragma unroll
    for (int off = 32; off > 0; off >>= 1) { s += __shfl_xor(s, off); sq += __shfl_xor(sq, off); }
    float mean = s * (1.f / 128.f);
    float var  = sq * (1.f / 128.f) - mean * mean;
    float inv  = rsqrtf(var + 1e-5f);
    out[(row0 + r) * 128 + l]      = (v0 - mean) * inv * n2w[l] + n2b[l];
    out[(row0 + r) * 128 + 64 + l] = (v1 - mean) * inv * n2w[64 + l] + n2b[64 + l];
  }
}

extern "C" void kernel_launch(void* const* d_in, const int* in_sizes, int n_in,
                              void* d_out, int out_size, void* d_ws, size_t ws_size,
                              hipStream_t stream) {
  const float* x     = (const float*)d_in[0];
  const float* wq    = (const float*)d_in[1];
  const float* wk    = (const float*)d_in[2];
  const float* wv    = (const float*)d_in[3];
  const float* lnq_w = (const float*)d_in[4];
  const float* lnq_b = (const float*)d_in[5];
  const float* lnk_w = (const float*)d_in[6];
  const float* lnk_b = (const float*)d_in[7];
  const float* lnv_w = (const float*)d_in[8];
  const float* lnv_b = (const float*)d_in[9];
  const float* rel   = (const float*)d_in[10];
  const float* gb    = (const float*)d_in[11];
  const float* alpha = (const float*)d_in[12];
  const float* wo    = (const float*)d_in[13];
  const float* bo    = (const float*)d_in[14];
  const float* w1    = (const float*)d_in[15];
  const float* b1    = (const float*)d_in[16];
  const float* w2    = (const float*)d_in[17];
  const float* b2    = (const float*)d_in[18];
  const float* n1w   = (const float*)d_in[19];
  const float* n1b   = (const float*)d_in[20];
  const float* n2w   = (const float*)d_in[21];
  const float* n2b   = (const float*)d_in[22];
  float* out = (float*)d_out;

  // ws: WcF | w1F | w2F | woF | biasT (602624 B) | xr (41.9 MB) | qP (41.9 MB). k,v planes in d_out.
  unsigned short* WcF = (unsigned short*)d_ws;     // 147456 us
  unsigned short* w1F = WcF + 147456;              // 65536
  unsigned short* w2F = w1F + 65536;               // 65536
  unsigned short* woF = w2F + 65536;               // 16384
  float* biasT = (float*)(woF + 16384);            // 3200 f32 -> ends at 602624 B
  unsigned short* xr = (unsigned short*)((char*)d_ws + 602624);

  const size_t NEED2 = 602624ULL + 41943040ULL;

  hipLaunchKernelGGL(prep2, dim3(584), dim3(256), 0, stream,
                     wq, wk, wv, w1, w2, wo, rel, gb, alpha, WcF, w1F, w2F, woF, biasT);

  unsigned short* qP = (unsigned short*)((char*)d_ws + NEED2);
  unsigned short* kP = (unsigned short*)d_out;
  unsigned short* vP = kP + (size_t)NROWS * 128;

  hipLaunchKernelGGL(conv_qkv, dim3(NROWS / 128, 3), dim3(256), 0, stream,
                     x, WcF, lnq_w, lnq_b, lnk_w, lnk_b, lnv_w, lnv_b, qP, kP, vP);
  hipLaunchKernelGGL(attn_wo, dim3(NB / 2), dim3(320), 0, stream,
                     x, qP, kP, vP, woF, biasT, bo, n1w, n1b, xr);
  hipLaunchKernelGGL(ffn_c, dim3(NROWS / 32), dim3(256), 0, stream,
                     xr, w1F, w2F, b1, b2, n2w, n2b, out);
}

// Round 6
// 337.867 us; speedup vs baseline: 1.2564x; 1.2564x over previous
//
#include <hip/hip_runtime.h>
#include <hip/hip_bf16.h>
#include <math.h>

#define NB 8192
#define NN 20
#define DD 128
#define HH 8
#define FFD 512
#define NROWS (NB * NN)          // 163840 total rows

typedef __attribute__((ext_vector_type(8))) short bf16x8;
typedef __attribute__((ext_vector_type(4))) float f32x4;

__device__ __forceinline__ unsigned short f2bf(float f) {
  union { __hip_bfloat16 h; unsigned short u; } cv; cv.h = __float2bfloat16(f); return cv.u;
}
__device__ __forceinline__ float bf2f(unsigned short u) {
  union { unsigned short u; __hip_bfloat16 h; } cv; cv.u = u; return __bfloat162float(cv.h);
}
__device__ __forceinline__ float gelu_t(float v) {
  float u = v * (0.7978845608f + 0.0356774081f * v * v);
  float e = __expf(2.f * u);
  float th = 1.f - 2.f / (e + 1.f);
  return 0.5f * v * (1.f + th);
}

// ======================= prep: weight frag swizzle + bias fuse =======================
__global__ __launch_bounds__(256) void prep2(
    const float* __restrict__ wq, const float* __restrict__ wk, const float* __restrict__ wv,
    const float* __restrict__ w1, const float* __restrict__ w2, const float* __restrict__ wo,
    const float* __restrict__ rel, const float* __restrict__ gb, const float* __restrict__ alpha,
    unsigned short* __restrict__ WcF, unsigned short* __restrict__ w1F,
    unsigned short* __restrict__ w2F, unsigned short* __restrict__ woF,
    float* __restrict__ biasT)
{
  int bid = blockIdx.x, t = threadIdx.x;
  if (bid < 288) {            // conv: per-projection frag planes [p][nt8][kc12][64][8]
    int nt = bid / 12, kc = bid % 12;
    for (int i = t; i < 512; i += 256) {
      int lane = i >> 3, j = i & 7;
      int k = kc * 32 + (lane >> 4) * 8 + j;
      int c = nt * 16 + (lane & 15);
      int kk = k >> 7, din = k & 127;
      int which = c >> 7, dout = c & 127;
      const float* w = (which == 0) ? wq : (which == 1) ? wk : wv;
      WcF[((nt * 12 + kc) * 64 + lane) * 8 + j] = f2bf(w[(dout * 128 + din) * 3 + kk]);
    }
  } else if (bid < 416) {     // w1: K=128 (kc 4), N=512 (nt 32)
    int tt = bid - 288; int nt = tt / 4, kc = tt % 4;
    for (int i = t; i < 512; i += 256) {
      int lane = i >> 3, j = i & 7;
      int k = kc * 32 + (lane >> 4) * 8 + j;
      int c = nt * 16 + (lane & 15);
      w1F[((nt * 4 + kc) * 64 + lane) * 8 + j] = f2bf(w1[k * 512 + c]);
    }
  } else if (bid < 544) {     // w2: K=512 (kc 16), N=128 (nt 8)
    int tt = bid - 416; int nt = tt / 16, kc = tt % 16;
    for (int i = t; i < 512; i += 256) {
      int lane = i >> 3, j = i & 7;
      int k = kc * 32 + (lane >> 4) * 8 + j;
      int c = nt * 16 + (lane & 15);
      w2F[((nt * 16 + kc) * 64 + lane) * 8 + j] = f2bf(w2[k * 128 + c]);
    }
  } else if (bid < 576) {     // wo: K=128 (kc 4), N=128 (nt 8)
    int tt = bid - 544; int nt = tt / 4, kc = tt % 4;
    for (int i = t; i < 512; i += 256) {
      int lane = i >> 3, j = i & 7;
      int k = kc * 32 + (lane >> 4) * 8 + j;
      int c = nt * 16 + (lane & 15);
      woF[((nt * 4 + kc) * 64 + lane) * 8 + j] = f2bf(wo[k * 128 + c]);
    }
  } else {                    // bias fuse
    int h = bid - 576; float a = alpha[0];
    for (int i = t; i < 400; i += 256) {
      int n = i / 20, m = i % 20;
      biasT[h * 400 + i] = rel[(n - m + 19) * 8 + h] + gb[h * 400 + i] * a;
    }
  }
}

// ======================= conv1d-QKV (R4, proven): per-projection 128x128 tile, LDS-resident B ====
__global__ __launch_bounds__(256, 3) void conv_qkv(
    const float* __restrict__ x, const unsigned short* __restrict__ WcF,
    const float* __restrict__ lnq_w, const float* __restrict__ lnq_b,
    const float* __restrict__ lnk_w, const float* __restrict__ lnk_b,
    const float* __restrict__ lnv_w, const float* __restrict__ lnv_b,
    unsigned short* __restrict__ qP, unsigned short* __restrict__ kP,
    unsigned short* __restrict__ vP)
{
  __shared__ __align__(16) unsigned short xA[130 * 136];
  __shared__ __align__(16) unsigned short Bb[2][8 * 64 * 8];

  const int t = threadIdx.x;
  const int w = t >> 6, l = t & 63;
  const int l15 = l & 15, l4 = l >> 4;
  const int p = blockIdx.y;
  const long g0 = (long)blockIdx.x * 128;
  const unsigned short* Wp = WcF + (size_t)p * 8 * 12 * 512;

  for (int i = t; i < 130 * 32; i += 256) {
    int r = i >> 5, c4 = i & 31;
    long g = g0 - 1 + r;
    long gc = g < 0 ? 0 : (g >= NROWS ? NROWS - 1 : g);
    float4 v = *(const float4*)(x + gc * 128 + c4 * 4);
    ushort4 pk; pk.x = f2bf(v.x); pk.y = f2bf(v.y); pk.z = f2bf(v.z); pk.w = f2bf(v.w);
    *(ushort4*)&xA[r * 136 + c4 * 4] = pk;
  }

  const int snt = t >> 5, sinner = t & 31;
  const unsigned short* sB = Wp + snt * 12 * 512 + sinner * 16;
  unsigned short* dB0 = &Bb[0][snt * 512 + sinner * 16];
  unsigned short* dB1 = &Bb[1][snt * 512 + sinner * 16];

  bf16x8 h0, h1;
  {
    bf16x8 a = *(const bf16x8*)(sB);
    bf16x8 b = *(const bf16x8*)(sB + 8);
    *(bf16x8*)dB0 = a; *(bf16x8*)(dB0 + 8) = b;
    h0 = *(const bf16x8*)(sB + 512);
    h1 = *(const bf16x8*)(sB + 512 + 8);
  }
  __syncthreads();

  const int rA0 = w * 32 + l15;
  const int rA1 = rA0 + 16;
  const int nA0 = (int)((g0 + rA0) % 20);
  const int nA1 = (int)((g0 + rA1) % 20);

  f32x4 acc[2][8];
  #pragma unroll
  for (int mt = 0; mt < 2; ++mt)
    #pragma unroll
    for (int nt = 0; nt < 8; ++nt) acc[mt][nt] = (f32x4){0.f, 0.f, 0.f, 0.f};

  const bf16x8 zz = {};
  for (int kc = 0; kc < 12; ++kc) {
    const int kk = kc >> 2, k4 = kc & 3;
    const bool m0 = (kk == 1) || ((kk == 0) ? (nA0 != 0) : (nA0 != 19));
    const bool m1 = (kk == 1) || ((kk == 0) ? (nA1 != 0) : (nA1 != 19));
    bf16x8 a0 = *(const bf16x8*)&xA[(rA0 + kk) * 136 + k4 * 32 + l4 * 8]; if (!m0) a0 = zz;
    bf16x8 a1 = *(const bf16x8*)&xA[(rA1 + kk) * 136 + k4 * 32 + l4 * 8]; if (!m1) a1 = zz;
    const unsigned short* bb = &Bb[kc & 1][l * 8];
    #pragma unroll
    for (int nt = 0; nt < 8; ++nt) {
      bf16x8 b = *(const bf16x8*)(bb + nt * 512);
      acc[0][nt] = __builtin_amdgcn_mfma_f32_16x16x32_bf16(a0, b, acc[0][nt], 0, 0, 0);
      acc[1][nt] = __builtin_amdgcn_mfma_f32_16x16x32_bf16(a1, b, acc[1][nt], 0, 0, 0);
    }
    if (kc < 11) {
      unsigned short* d = (kc & 1) ? dB0 : dB1;
      *(bf16x8*)d = h0; *(bf16x8*)(d + 8) = h1;
    }
    if (kc < 10) {
      h0 = *(const bf16x8*)(sB + (kc + 2) * 512);
      h1 = *(const bf16x8*)(sB + (kc + 2) * 512 + 8);
    }
    __syncthreads();
  }

  const float* lw = (p == 0) ? lnq_w : (p == 1) ? lnk_w : lnv_w;
  const float* lb = (p == 0) ? lnq_b : (p == 1) ? lnk_b : lnv_b;
  float gw8[8], gb8[8];
  #pragma unroll
  for (int nt = 0; nt < 8; ++nt) { gw8[nt] = lw[nt * 16 + l15]; gb8[nt] = lb[nt * 16 + l15]; }

  #pragma unroll
  for (int mt = 0; mt < 2; ++mt) {
    float s[4], qq[4];
    #pragma unroll
    for (int j = 0; j < 4; ++j) {
      float a0 = 0.f, a1 = 0.f;
      #pragma unroll
      for (int nt = 0; nt < 8; ++nt) { float v = acc[mt][nt][j]; a0 += v; a1 = fmaf(v, v, a1); }
      s[j] = a0; qq[j] = a1;
    }
    #pragma unroll
    for (int off = 1; off < 16; off <<= 1) {
      #pragma unroll
      for (int j = 0; j < 4; ++j) { s[j] += __shfl_xor(s[j], off); qq[j] += __shfl_xor(qq[j], off); }
    }
    #pragma unroll
    for (int j = 0; j < 4; ++j) {
      float mean = s[j] * (1.f / 128.f);
      float var  = qq[j] * (1.f / 128.f) - mean * mean;
      float inv  = rsqrtf(var + 1e-5f);
      int lr = w * 32 + mt * 16 + l4 * 4 + j;
      #pragma unroll
      for (int nt = 0; nt < 8; ++nt)
        xA[lr * 136 + nt * 16 + l15] = f2bf((acc[mt][nt][j] - mean) * inv * gw8[nt] + gb8[nt]);
    }
  }
  __syncthreads();

  unsigned short* plane = (p == 0) ? qP : (p == 1) ? kP : vP;
  const float qs = (p == 0) ? 0.25f : 1.0f;
  for (int i = t; i < 128 * 16; i += 256) {
    int r = i >> 4, c8 = i & 15;
    bf16x8 ob = *(const bf16x8*)&xA[r * 136 + c8 * 8];
    long grow = g0 + r;
    const float* xr8 = x + grow * 128 + c8 * 8;
    float4 xa = *(const float4*)xr8;
    float4 xb = *(const float4*)(xr8 + 4);
    bf16x8 o;
    o[0] = (short)f2bf((xa.x + bf2f((unsigned short)ob[0])) * qs);
    o[1] = (short)f2bf((xa.y + bf2f((unsigned short)ob[1])) * qs);
    o[2] = (short)f2bf((xa.z + bf2f((unsigned short)ob[2])) * qs);
    o[3] = (short)f2bf((xa.w + bf2f((unsigned short)ob[3])) * qs);
    o[4] = (short)f2bf((xb.x + bf2f((unsigned short)ob[4])) * qs);
    o[5] = (short)f2bf((xb.y + bf2f((unsigned short)ob[5])) * qs);
    o[6] = (short)f2bf((xb.z + bf2f((unsigned short)ob[6])) * qs);
    o[7] = (short)f2bf((xb.w + bf2f((unsigned short)ob[7])) * qs);
    *(bf16x8*)&plane[grow * 128 + c8 * 8] = o;
  }
}

// ======================= attention + wo + LN1 (R3-proven 256-thread version) =======================
__global__ __launch_bounds__(256, 3) void attn_wo(
    const float* __restrict__ x,
    const unsigned short* __restrict__ qP, const unsigned short* __restrict__ kP,
    const unsigned short* __restrict__ vP,
    const unsigned short* __restrict__ woF, const float* __restrict__ biasT,
    const float* __restrict__ bo,
    const float* __restrict__ n1w, const float* __restrict__ n1b,
    unsigned short* __restrict__ xr)
{
  __shared__ __align__(16) char smem[47104];
  unsigned short* ks  = (unsigned short*)smem;
  unsigned short* vs  = (unsigned short*)(smem + 10880);
  unsigned short* ctx = ks;
  float* scr = (float*)(smem + 21760);

  const int t = threadIdx.x;
  const int w = t >> 6, l = t & 63;
  const int l15 = l & 15, l4 = l >> 4;
  const int eb = blockIdx.x * 2;
  const float* xg = x + (size_t)eb * (NN * DD);

  for (int i = t; i < 1280; i += 256) {
    int proj = i / 640, r = i % 640;
    int e = r / 320, rr = r % 320;
    int n = rr / 16, c8 = rr % 16;
    const unsigned short* src = (proj == 0 ? kP : vP) + (((size_t)(eb + e) * 20 + n) * 128 + c8 * 8);
    unsigned short* dst = (proj == 0 ? ks : vs) + ((e * 20 + n) * 136 + c8 * 8);
    *(bf16x8*)dst = *(const bf16x8*)src;
  }
  __syncthreads();

  float pm[2][20];
  #pragma unroll
  for (int pass = 0; pass < 2; ++pass) {
    int i = t + pass * 256;
    if (i < 320) {
      int e = i / 160, hh = (i / 20) % 8, n = i % 20;
      const unsigned short* qr = qP + ((size_t)(eb + e) * 20 + n) * 128 + hh * 16;
      bf16x8 qa = *(const bf16x8*)qr, qb = *(const bf16x8*)(qr + 8);
      float q[16];
      #pragma unroll
      for (int j = 0; j < 8; ++j) { q[j] = bf2f((unsigned short)qa[j]); q[8 + j] = bf2f((unsigned short)qb[j]); }
      float bias[20];
      const float* bp = &biasT[(hh * 20 + n) * 20];
      #pragma unroll
      for (int m4 = 0; m4 < 5; ++m4) {
        float4 bv = *(const float4*)(bp + m4 * 4);
        bias[m4 * 4] = bv.x; bias[m4 * 4 + 1] = bv.y; bias[m4 * 4 + 2] = bv.z; bias[m4 * 4 + 3] = bv.w;
      }
      float mx = -1e30f;
      #pragma unroll
      for (int m = 0; m < 20; ++m) {
        const unsigned short* kr = &ks[(e * 20 + m) * 136 + hh * 16];
        bf16x8 ka = *(const bf16x8*)kr, kb = *(const bf16x8*)(kr + 8);
        float sv = bias[m];
        #pragma unroll
        for (int j = 0; j < 8; ++j) {
          sv = fmaf(q[j], bf2f((unsigned short)ka[j]), sv);
          sv = fmaf(q[8 + j], bf2f((unsigned short)kb[j]), sv);
        }
        pm[pass][m] = sv; mx = fmaxf(mx, sv);
      }
      float sum = 0.f;
      #pragma unroll
      for (int m = 0; m < 20; ++m) { pm[pass][m] = __expf(pm[pass][m] - mx); sum += pm[pass][m]; }
      float rs = 1.f / sum;
      #pragma unroll
      for (int m = 0; m < 20; ++m) pm[pass][m] *= rs;
    }
  }
  __syncthreads();

  #pragma unroll
  for (int pass = 0; pass < 2; ++pass) {
    int i = t + pass * 256;
    if (i < 320) {
      int e = i / 160, hh = (i / 20) % 8, n = i % 20;
      float c[16];
      #pragma unroll
      for (int j = 0; j < 16; ++j) c[j] = 0.f;
      #pragma unroll
      for (int m = 0; m < 20; ++m) {
        const unsigned short* vr = &vs[(e * 20 + m) * 136 + hh * 16];
        bf16x8 va = *(const bf16x8*)vr, vb = *(const bf16x8*)(vr + 8);
        float pv = pm[pass][m];
        #pragma unroll
        for (int j = 0; j < 8; ++j) {
          c[j] = fmaf(pv, bf2f((unsigned short)va[j]), c[j]);
          c[8 + j] = fmaf(pv, bf2f((unsigned short)vb[j]), c[8 + j]);
        }
      }
      bf16x8 c0, c1;
      #pragma unroll
      for (int j = 0; j < 8; ++j) { c0[j] = (short)f2bf(c[j]); c1[j] = (short)f2bf(c[8 + j]); }
      *(bf16x8*)&ctx[(e * 20 + n) * 136 + hh * 16] = c0;
      *(bf16x8*)&ctx[(e * 20 + n) * 136 + hh * 16 + 8] = c1;
    }
  }
  __syncthreads();

  int emap[3], nmap[3];
  #pragma unroll
  for (int mt = 0; mt < 3; ++mt) {
    int g = mt * 16 + l15;
    int e = g / 20, n = g - e * 20;
    if (e > 1) { e = 1; n = 19; }
    emap[mt] = e; nmap[mt] = n;
  }
  {
    f32x4 acc[3][2];
    #pragma unroll
    for (int mt = 0; mt < 3; ++mt)
      #pragma unroll
      for (int i = 0; i < 2; ++i) acc[mt][i] = (f32x4){0.f, 0.f, 0.f, 0.f};
    #pragma unroll
    for (int kc = 0; kc < 4; ++kc) {
      bf16x8 a[3], b[2];
      #pragma unroll
      for (int mt = 0; mt < 3; ++mt)
        a[mt] = *(const bf16x8*)&ctx[(emap[mt] * 20 + nmap[mt]) * 136 + kc * 32 + l4 * 8];
      #pragma unroll
      for (int i = 0; i < 2; ++i) {
        int ntg = w * 2 + i;
        b[i] = *(const bf16x8*)&woF[((ntg * 4 + kc) * 64 + l) * 8];
      }
      #pragma unroll
      for (int mt = 0; mt < 3; ++mt)
        #pragma unroll
        for (int i = 0; i < 2; ++i)
          acc[mt][i] = __builtin_amdgcn_mfma_f32_16x16x32_bf16(a[mt], b[i], acc[mt][i], 0, 0, 0);
    }
    #pragma unroll
    for (int mt = 0; mt < 3; ++mt)
      #pragma unroll
      for (int i = 0; i < 2; ++i) {
        int col = (w * 2 + i) * 16 + l15;
        int rbase = mt * 16 + l4 * 4;
        #pragma unroll
        for (int j = 0; j < 4; ++j) scr[(rbase + j) * 132 + col] = acc[mt][i][j];
      }
  }
  __syncthreads();

  for (int r = w; r < 40; r += 4) {
    int e = r / 20, n = r % 20;
    float v0 = scr[r * 132 + l]      + bo[l]      + xg[e * 2560 + n * 128 + l];
    float v1 = scr[r * 132 + 64 + l] + bo[64 + l] + xg[e * 2560 + n * 128 + 64 + l];
    float s = v0 + v1, sq = v0 * v0 + v1 * v1;
    #pragma unroll
    for (int off = 32; off > 0; off >>= 1) { s += __shfl_xor(s, off); sq += __shfl_xor(sq, off); }
    float mean = s * (1.f / 128.f);
    float var  = sq * (1.f / 128.f) - mean * mean;
    float inv  = rsqrtf(var + 1e-5f);
    size_t ro = ((size_t)(eb + e) * 20 + n) * 128;
    xr[ro + l]      = f2bf((v0 - mean) * inv * n1w[l] + n1b[l]);
    xr[ro + 64 + l] = f2bf((v1 - mean) * inv * n1w[64 + l] + n1b[64 + l]);
  }
}

// ======================= FFN + LN2 v3: M=64 rows/block, 2 ffn-col phases, 3 blocks/CU =============
// LDS: xrb [64][136] bf16 (17408) + h_half [64][264] bf16 (33792, aliased by scr [64][132] f32).
// Wave w owns rows all 64 (4 M-tiles) x its nt columns. acc2 (wo-output) held across phases.
__global__ __launch_bounds__(256, 3) void ffn_c(
    const unsigned short* __restrict__ xr,
    const unsigned short* __restrict__ w1F, const unsigned short* __restrict__ w2F,
    const float* __restrict__ b1, const float* __restrict__ b2,
    const float* __restrict__ n2w, const float* __restrict__ n2b,
    float* __restrict__ out)
{
  __shared__ __align__(16) char smem[17408 + 33792];
  unsigned short* xrb = (unsigned short*)smem;              // [64][136]
  unsigned short* hh  = (unsigned short*)(smem + 17408);    // [64][264]
  float* sc2          = (float*)(smem + 17408);             // [64][132] aliases hh

  const int t = threadIdx.x;
  const int w = t >> 6, l = t & 63;
  const int l15 = l & 15, l4 = l >> 4;
  const size_t row0 = (size_t)blockIdx.x * 64;

  for (int i = t; i < 1024; i += 256) {    // 64 rows x 16 chunks
    int r = i >> 4, c8 = i & 15;
    *(bf16x8*)&xrb[r * 136 + c8 * 8] = *(const bf16x8*)&xr[(row0 + r) * 128 + c8 * 8];
  }
  __syncthreads();

  f32x4 acc2[4][2];
  #pragma unroll
  for (int mt = 0; mt < 4; ++mt)
    #pragma unroll
    for (int i = 0; i < 2; ++i) acc2[mt][i] = (f32x4){0.f, 0.f, 0.f, 0.f};

  #pragma unroll
  for (int phase = 0; phase < 2; ++phase) {
    // ---- FFN1 for cols [phase*256, phase*256+256), in two nt-pairs per wave ----
    #pragma unroll
    for (int pair = 0; pair < 2; ++pair) {
      f32x4 acc1[4][2];
      #pragma unroll
      for (int mt = 0; mt < 4; ++mt)
        #pragma unroll
        for (int i = 0; i < 2; ++i) acc1[mt][i] = (f32x4){0.f, 0.f, 0.f, 0.f};
      #pragma unroll
      for (int kc = 0; kc < 4; ++kc) {
        bf16x8 a[4];
        #pragma unroll
        for (int mt = 0; mt < 4; ++mt)
          a[mt] = *(const bf16x8*)&xrb[(mt * 16 + l15) * 136 + kc * 32 + l4 * 8];
        #pragma unroll
        for (int i = 0; i < 2; ++i) {
          int ntg = phase * 16 + w * 4 + pair * 2 + i;
          bf16x8 b = *(const bf16x8*)&w1F[((ntg * 4 + kc) * 64 + l) * 8];
          #pragma unroll
          for (int mt = 0; mt < 4; ++mt)
            acc1[mt][i] = __builtin_amdgcn_mfma_f32_16x16x32_bf16(a[mt], b, acc1[mt][i], 0, 0, 0);
        }
      }
      // gelu + write into h_half (local cols)
      #pragma unroll
      for (int i = 0; i < 2; ++i) {
        int ntg = phase * 16 + w * 4 + pair * 2 + i;
        int lc = (w * 4 + pair * 2 + i) * 16 + l15;      // 0..255
        float b1v = b1[ntg * 16 + l15];
        #pragma unroll
        for (int mt = 0; mt < 4; ++mt)
          #pragma unroll
          for (int j = 0; j < 4; ++j) {
            float v = acc1[mt][i][j] + b1v;
            hh[(mt * 16 + l4 * 4 + j) * 264 + lc] = f2bf(gelu_t(v));
          }
      }
    }
    __syncthreads();

    // ---- FFN2 partial: K = cols of this phase (8 kc steps) ----
    #pragma unroll
    for (int kk = 0; kk < 8; ++kk) {
      bf16x8 a[4];
      #pragma unroll
      for (int mt = 0; mt < 4; ++mt)
        a[mt] = *(const bf16x8*)&hh[(mt * 16 + l15) * 264 + kk * 32 + l4 * 8];
      #pragma unroll
      for (int i = 0; i < 2; ++i) {
        int ntg = w * 2 + i;
        int kcg = phase * 8 + kk;
        bf16x8 b = *(const bf16x8*)&w2F[((ntg * 16 + kcg) * 64 + l) * 8];
        #pragma unroll
        for (int mt = 0; mt < 4; ++mt)
          acc2[mt][i] = __builtin_amdgcn_mfma_f32_16x16x32_bf16(a[mt], b, acc2[mt][i], 0, 0, 0);
      }
    }
    __syncthreads();   // hh consumed; safe to overwrite next phase (or alias as sc2)
  }

  // ---- store acc2 -> sc2 (aliases hh) ----
  #pragma unroll
  for (int mt = 0; mt < 4; ++mt)
    #pragma unroll
    for (int i = 0; i < 2; ++i) {
      int col = (w * 2 + i) * 16 + l15;
      int rbase = mt * 16 + l4 * 4;
      #pragma unroll
      for (int j = 0; j < 4; ++j) sc2[(rbase + j) * 132 + col] = acc2[mt][i][j];
    }
  __syncthreads();

  // ---- LN2(xr + ffn + b2) -> out ----
  for (int r = w; r < 64; r += 4) {
    float v0 = sc2[r * 132 + l]      + b2[l]      + bf2f(xrb[r * 136 + l]);
    float v1 = sc2[r * 132 + 64 + l] + b2[64 + l] + bf2f(xrb[r * 136 + 64 + l]);
    float s = v0 + v1, sq = v0 * v0 + v1 * v1;
    #pragma unroll
    for (int off = 32; off > 0; off >>= 1) { s += __shfl_xor(s, off); sq += __shfl_xor(sq, off); }
    float mean = s * (1.f / 128.f);
    float var  = sq * (1.f / 128.f) - mean * mean;
    float inv  = rsqrtf(var + 1e-5f);
    out[(row0 + r) * 128 + l]      = (v0 - mean) * inv * n2w[l] + n2b[l];
    out[(row0 + r) * 128 + 64 + l] = (v1 - mean) * inv * n2w[64 + l] + n2b[64 + l];
  }
}

extern "C" void kernel_launch(void* const* d_in, const int* in_sizes, int n_in,
                              void* d_out, int out_size, void* d_ws, size_t ws_size,
                              hipStream_t stream) {
  const float* x     = (const float*)d_in[0];
  const float* wq    = (const float*)d_in[1];
  const float* wk    = (const float*)d_in[2];
  const float* wv    = (const float*)d_in[3];
  const float* lnq_w = (const float*)d_in[4];
  const float* lnq_b = (const float*)d_in[5];
  const float* lnk_w = (const float*)d_in[6];
  const float* lnk_b = (const float*)d_in[7];
  const float* lnv_w = (const float*)d_in[8];
  const float* lnv_b = (const float*)d_in[9];
  const float* rel   = (const float*)d_in[10];
  const float* gb    = (const float*)d_in[11];
  const float* alpha = (const float*)d_in[12];
  const float* wo    = (const float*)d_in[13];
  const float* bo    = (const float*)d_in[14];
  const float* w1    = (const float*)d_in[15];
  const float* b1    = (const float*)d_in[16];
  const float* w2    = (const float*)d_in[17];
  const float* b2    = (const float*)d_in[18];
  const float* n1w   = (const float*)d_in[19];
  const float* n1b   = (const float*)d_in[20];
  const float* n2w   = (const float*)d_in[21];
  const float* n2b   = (const float*)d_in[22];
  float* out = (float*)d_out;

  // ws: WcF | w1F | w2F | woF | biasT (602624 B) | xr (41.9 MB) | qP (41.9 MB). k,v planes in d_out.
  unsigned short* WcF = (unsigned short*)d_ws;     // 147456 us
  unsigned short* w1F = WcF + 147456;              // 65536
  unsigned short* w2F = w1F + 65536;               // 65536
  unsigned short* woF = w2F + 65536;               // 16384
  float* biasT = (float*)(woF + 16384);            // 3200 f32 -> ends at 602624 B
  unsigned short* xr = (unsigned short*)((char*)d_ws + 602624);

  const size_t NEED2 = 602624ULL + 41943040ULL;

  hipLaunchKernelGGL(prep2, dim3(584), dim3(256), 0, stream,
                     wq, wk, wv, w1, w2, wo, rel, gb, alpha, WcF, w1F, w2F, woF, biasT);

  unsigned short* qP = (unsigned short*)((char*)d_ws + NEED2);
  unsigned short* kP = (unsigned short*)d_out;
  unsigned short* vP = kP + (size_t)NROWS * 128;

  hipLaunchKernelGGL(conv_qkv, dim3(NROWS / 128, 3), dim3(256), 0, stream,
                     x, WcF, lnq_w, lnq_b, lnk_w, lnk_b, lnv_w, lnv_b, qP, kP, vP);
  hipLaunchKernelGGL(attn_wo, dim3(NB / 2), dim3(256), 0, stream,
                     x, qP, kP, vP, woF, biasT, bo, n1w, n1b, xr);
  hipLaunchKernelGGL(ffn_c, dim3(NROWS / 64), dim3(256), 0, stream,
                     xr, w1F, w2F, b1, b2, n2w, n2b, out);
}

// Round 7
// 335.711 us; speedup vs baseline: 1.2645x; 1.0064x over previous
//
#include <hip/hip_runtime.h>
#include <hip/hip_bf16.h>
#include <math.h>

#define NB 8192
#define NN 20
#define DD 128
#define HH 8
#define FFD 512
#define NROWS (NB * NN)          // 163840 total rows

typedef __attribute__((ext_vector_type(8))) short bf16x8;
typedef __attribute__((ext_vector_type(4))) float f32x4;

__device__ __forceinline__ unsigned short f2bf(float f) {
  union { __hip_bfloat16 h; unsigned short u; } cv; cv.h = __float2bfloat16(f); return cv.u;
}
__device__ __forceinline__ float bf2f(unsigned short u) {
  union { unsigned short u; __hip_bfloat16 h; } cv; cv.u = u; return __bfloat162float(cv.h);
}
__device__ __forceinline__ float gelu_t(float v) {
  float u = v * (0.7978845608f + 0.0356774081f * v * v);
  float e = __expf(2.f * u);
  float th = 1.f - 2.f / (e + 1.f);
  return 0.5f * v * (1.f + th);
}

// ======================= prep: weight frag swizzle + bias fuse =======================
__global__ __launch_bounds__(256) void prep2(
    const float* __restrict__ wq, const float* __restrict__ wk, const float* __restrict__ wv,
    const float* __restrict__ w1, const float* __restrict__ w2, const float* __restrict__ wo,
    const float* __restrict__ rel, const float* __restrict__ gb, const float* __restrict__ alpha,
    unsigned short* __restrict__ WcF, unsigned short* __restrict__ w1F,
    unsigned short* __restrict__ w2F, unsigned short* __restrict__ woF,
    float* __restrict__ biasT)
{
  int bid = blockIdx.x, t = threadIdx.x;
  if (bid < 288) {            // conv: per-projection frag planes [p][nt8][kc12][64][8]
    int nt = bid / 12, kc = bid % 12;
    for (int i = t; i < 512; i += 256) {
      int lane = i >> 3, j = i & 7;
      int k = kc * 32 + (lane >> 4) * 8 + j;
      int c = nt * 16 + (lane & 15);
      int kk = k >> 7, din = k & 127;
      int which = c >> 7, dout = c & 127;
      const float* w = (which == 0) ? wq : (which == 1) ? wk : wv;
      WcF[((nt * 12 + kc) * 64 + lane) * 8 + j] = f2bf(w[(dout * 128 + din) * 3 + kk]);
    }
  } else if (bid < 416) {     // w1: K=128 (kc 4), N=512 (nt 32)
    int tt = bid - 288; int nt = tt / 4, kc = tt % 4;
    for (int i = t; i < 512; i += 256) {
      int lane = i >> 3, j = i & 7;
      int k = kc * 32 + (lane >> 4) * 8 + j;
      int c = nt * 16 + (lane & 15);
      w1F[((nt * 4 + kc) * 64 + lane) * 8 + j] = f2bf(w1[k * 512 + c]);
    }
  } else if (bid < 544) {     // w2: K=512 (kc 16), N=128 (nt 8)
    int tt = bid - 416; int nt = tt / 16, kc = tt % 16;
    for (int i = t; i < 512; i += 256) {
      int lane = i >> 3, j = i & 7;
      int k = kc * 32 + (lane >> 4) * 8 + j;
      int c = nt * 16 + (lane & 15);
      w2F[((nt * 16 + kc) * 64 + lane) * 8 + j] = f2bf(w2[k * 128 + c]);
    }
  } else if (bid < 576) {     // wo: K=128 (kc 4), N=128 (nt 8)
    int tt = bid - 544; int nt = tt / 4, kc = tt % 4;
    for (int i = t; i < 512; i += 256) {
      int lane = i >> 3, j = i & 7;
      int k = kc * 32 + (lane >> 4) * 8 + j;
      int c = nt * 16 + (lane & 15);
      woF[((nt * 4 + kc) * 64 + lane) * 8 + j] = f2bf(wo[k * 128 + c]);
    }
  } else {                    // bias fuse
    int h = bid - 576; float a = alpha[0];
    for (int i = t; i < 400; i += 256) {
      int n = i / 20, m = i % 20;
      biasT[h * 400 + i] = rel[(n - m + 19) * 8 + h] + gb[h * 400 + i] * a;
    }
  }
}

// ======================= conv1d-QKV v4: LDS-resident B + zero-global-read epilogue ==============
// Per R4 structure; epilogue now stashes the bf16 residual from staged xA into regs, so the
// copy-out does no global reads (saves ~84 MB HBM re-read of x).
__global__ __launch_bounds__(256, 3) void conv_qkv(
    const float* __restrict__ x, const unsigned short* __restrict__ WcF,
    const float* __restrict__ lnq_w, const float* __restrict__ lnq_b,
    const float* __restrict__ lnk_w, const float* __restrict__ lnk_b,
    const float* __restrict__ lnv_w, const float* __restrict__ lnv_b,
    unsigned short* __restrict__ qP, unsigned short* __restrict__ kP,
    unsigned short* __restrict__ vP)
{
  __shared__ __align__(16) unsigned short xA[130 * 136];
  __shared__ __align__(16) unsigned short Bb[2][8 * 64 * 8];

  const int t = threadIdx.x;
  const int w = t >> 6, l = t & 63;
  const int l15 = l & 15, l4 = l >> 4;
  const int p = blockIdx.y;
  const long g0 = (long)blockIdx.x * 128;
  const unsigned short* Wp = WcF + (size_t)p * 8 * 12 * 512;

  for (int i = t; i < 130 * 32; i += 256) {
    int r = i >> 5, c4 = i & 31;
    long g = g0 - 1 + r;
    long gc = g < 0 ? 0 : (g >= NROWS ? NROWS - 1 : g);
    float4 v = *(const float4*)(x + gc * 128 + c4 * 4);
    ushort4 pk; pk.x = f2bf(v.x); pk.y = f2bf(v.y); pk.z = f2bf(v.z); pk.w = f2bf(v.w);
    *(ushort4*)&xA[r * 136 + c4 * 4] = pk;
  }

  const int snt = t >> 5, sinner = t & 31;
  const unsigned short* sB = Wp + snt * 12 * 512 + sinner * 16;
  unsigned short* dB0 = &Bb[0][snt * 512 + sinner * 16];
  unsigned short* dB1 = &Bb[1][snt * 512 + sinner * 16];

  bf16x8 h0, h1;
  {
    bf16x8 a = *(const bf16x8*)(sB);
    bf16x8 b = *(const bf16x8*)(sB + 8);
    *(bf16x8*)dB0 = a; *(bf16x8*)(dB0 + 8) = b;
    h0 = *(const bf16x8*)(sB + 512);
    h1 = *(const bf16x8*)(sB + 512 + 8);
  }
  __syncthreads();

  const int rA0 = w * 32 + l15;
  const int rA1 = rA0 + 16;
  const int nA0 = (int)((g0 + rA0) % 20);
  const int nA1 = (int)((g0 + rA1) % 20);

  f32x4 acc[2][8];
  #pragma unroll
  for (int mt = 0; mt < 2; ++mt)
    #pragma unroll
    for (int nt = 0; nt < 8; ++nt) acc[mt][nt] = (f32x4){0.f, 0.f, 0.f, 0.f};

  const bf16x8 zz = {};
  for (int kc = 0; kc < 12; ++kc) {
    const int kk = kc >> 2, k4 = kc & 3;
    const bool m0 = (kk == 1) || ((kk == 0) ? (nA0 != 0) : (nA0 != 19));
    const bool m1 = (kk == 1) || ((kk == 0) ? (nA1 != 0) : (nA1 != 19));
    bf16x8 a0 = *(const bf16x8*)&xA[(rA0 + kk) * 136 + k4 * 32 + l4 * 8]; if (!m0) a0 = zz;
    bf16x8 a1 = *(const bf16x8*)&xA[(rA1 + kk) * 136 + k4 * 32 + l4 * 8]; if (!m1) a1 = zz;
    const unsigned short* bb = &Bb[kc & 1][l * 8];
    #pragma unroll
    for (int nt = 0; nt < 8; ++nt) {
      bf16x8 b = *(const bf16x8*)(bb + nt * 512);
      acc[0][nt] = __builtin_amdgcn_mfma_f32_16x16x32_bf16(a0, b, acc[0][nt], 0, 0, 0);
      acc[1][nt] = __builtin_amdgcn_mfma_f32_16x16x32_bf16(a1, b, acc[1][nt], 0, 0, 0);
    }
    if (kc < 11) {
      unsigned short* d = (kc & 1) ? dB0 : dB1;
      *(bf16x8*)d = h0; *(bf16x8*)(d + 8) = h1;
    }
    if (kc < 10) {
      h0 = *(const bf16x8*)(sB + (kc + 2) * 512);
      h1 = *(const bf16x8*)(sB + (kc + 2) * 512 + 8);
    }
    __syncthreads();
  }

  // ---- stash residual x (bf16, staged rows r+1) for this thread's copy-out slots ----
  bf16x8 xres[8];
  #pragma unroll
  for (int it = 0; it < 8; ++it) {
    int i = t + it * 256;
    int r = i >> 4, c8 = i & 15;
    xres[it] = *(const bf16x8*)&xA[(r + 1) * 136 + c8 * 8];
  }
  __syncthreads();   // all stashes complete before LN output overwrites xA

  // ---- wave-local LN -> xA rows 0..127 (obuf) ----
  const float* lw = (p == 0) ? lnq_w : (p == 1) ? lnk_w : lnv_w;
  const float* lb = (p == 0) ? lnq_b : (p == 1) ? lnk_b : lnv_b;
  float gw8[8], gb8[8];
  #pragma unroll
  for (int nt = 0; nt < 8; ++nt) { gw8[nt] = lw[nt * 16 + l15]; gb8[nt] = lb[nt * 16 + l15]; }

  #pragma unroll
  for (int mt = 0; mt < 2; ++mt) {
    float s[4], qq[4];
    #pragma unroll
    for (int j = 0; j < 4; ++j) {
      float a0 = 0.f, a1 = 0.f;
      #pragma unroll
      for (int nt = 0; nt < 8; ++nt) { float v = acc[mt][nt][j]; a0 += v; a1 = fmaf(v, v, a1); }
      s[j] = a0; qq[j] = a1;
    }
    #pragma unroll
    for (int off = 1; off < 16; off <<= 1) {
      #pragma unroll
      for (int j = 0; j < 4; ++j) { s[j] += __shfl_xor(s[j], off); qq[j] += __shfl_xor(qq[j], off); }
    }
    #pragma unroll
    for (int j = 0; j < 4; ++j) {
      float mean = s[j] * (1.f / 128.f);
      float var  = qq[j] * (1.f / 128.f) - mean * mean;
      float inv  = rsqrtf(var + 1e-5f);
      int lr = w * 32 + mt * 16 + l4 * 4 + j;
      #pragma unroll
      for (int nt = 0; nt < 8; ++nt)
        xA[lr * 136 + nt * 16 + l15] = f2bf((acc[mt][nt][j] - mean) * inv * gw8[nt] + gb8[nt]);
    }
  }
  __syncthreads();

  // ---- copy-out: plane = (x_bf16 + LN)*qs — no global reads ----
  unsigned short* plane = (p == 0) ? qP : (p == 1) ? kP : vP;
  const float qs = (p == 0) ? 0.25f : 1.0f;
  #pragma unroll
  for (int it = 0; it < 8; ++it) {
    int i = t + it * 256;
    int r = i >> 4, c8 = i & 15;
    bf16x8 ob = *(const bf16x8*)&xA[r * 136 + c8 * 8];
    bf16x8 o;
    #pragma unroll
    for (int j = 0; j < 8; ++j)
      o[j] = (short)f2bf((bf2f((unsigned short)xres[it][j]) + bf2f((unsigned short)ob[j])) * qs);
    *(bf16x8*)&plane[(g0 + r) * 128 + c8 * 8] = o;
  }
}

// ======================= attn_wo v3: 4 elements/block, scr aliases vs (bf16), 5 barriers ========
// LDS 43520 B -> 3 blocks/CU:
//   ks [4][20][136] bf16 @0      (21760)   ctx aliases after QK
//   vs [4][20][136] bf16 @21760  (21760)   scr [80][136] bf16 aliases after PV (exact fit)
__global__ __launch_bounds__(256, 3) void attn_wo(
    const float* __restrict__ x,
    const unsigned short* __restrict__ qP, const unsigned short* __restrict__ kP,
    const unsigned short* __restrict__ vP,
    const unsigned short* __restrict__ woF, const float* __restrict__ biasT,
    const float* __restrict__ bo,
    const float* __restrict__ n1w, const float* __restrict__ n1b,
    unsigned short* __restrict__ xr)
{
  __shared__ __align__(16) char smem[43520];
  unsigned short* ks  = (unsigned short*)smem;
  unsigned short* vs  = (unsigned short*)(smem + 21760);
  unsigned short* ctx = ks;                         // alias after QK
  unsigned short* scr = vs;                         // alias after PV (wo output, bf16 [80][136])

  const int t = threadIdx.x;
  const int w = t >> 6, l = t & 63;
  const int l15 = l & 15, l4 = l >> 4;
  const int eb = blockIdx.x * 4;

  // ---- stage k,v (4 elements) ----
  for (int i = t; i < 2560; i += 256) {
    int proj = i / 1280, r = i % 1280;
    int e = r / 320, rr = r % 320;
    int n = rr / 16, c8 = rr % 16;
    const unsigned short* src = (proj == 0 ? kP : vP) + (((size_t)(eb + e) * 20 + n) * 128 + c8 * 8);
    unsigned short* dst = (proj == 0 ? ks : vs) + ((e * 20 + n) * 136 + c8 * 8);
    *(bf16x8*)dst = *(const bf16x8*)src;
  }
  __syncthreads();

  // ---- QK + softmax: 640 jobs, 3 passes ----
  float pm[3][20];
  #pragma unroll
  for (int pass = 0; pass < 3; ++pass) {
    int i = t + pass * 256;
    if (i < 640) {
      int e = i / 160, hh = (i / 20) % 8, n = i % 20;
      const unsigned short* qr = qP + ((size_t)(eb + e) * 20 + n) * 128 + hh * 16;
      bf16x8 qa = *(const bf16x8*)qr, qb = *(const bf16x8*)(qr + 8);
      float q[16];
      #pragma unroll
      for (int j = 0; j < 8; ++j) { q[j] = bf2f((unsigned short)qa[j]); q[8 + j] = bf2f((unsigned short)qb[j]); }
      float bias[20];
      const float* bp = &biasT[(hh * 20 + n) * 20];
      #pragma unroll
      for (int m4 = 0; m4 < 5; ++m4) {
        float4 bv = *(const float4*)(bp + m4 * 4);
        bias[m4 * 4] = bv.x; bias[m4 * 4 + 1] = bv.y; bias[m4 * 4 + 2] = bv.z; bias[m4 * 4 + 3] = bv.w;
      }
      float mx = -1e30f;
      #pragma unroll
      for (int m = 0; m < 20; ++m) {
        const unsigned short* kr = &ks[(e * 20 + m) * 136 + hh * 16];
        bf16x8 ka = *(const bf16x8*)kr, kb = *(const bf16x8*)(kr + 8);
        float sv = bias[m];
        #pragma unroll
        for (int j = 0; j < 8; ++j) {
          sv = fmaf(q[j], bf2f((unsigned short)ka[j]), sv);
          sv = fmaf(q[8 + j], bf2f((unsigned short)kb[j]), sv);
        }
        pm[pass][m] = sv; mx = fmaxf(mx, sv);
      }
      float sum = 0.f;
      #pragma unroll
      for (int m = 0; m < 20; ++m) { pm[pass][m] = __expf(pm[pass][m] - mx); sum += pm[pass][m]; }
      float rs = 1.f / sum;
      #pragma unroll
      for (int m = 0; m < 20; ++m) pm[pass][m] *= rs;
    }
  }
  __syncthreads();   // ks fully consumed

  // ---- PV -> ctx (ks region) ----
  #pragma unroll
  for (int pass = 0; pass < 3; ++pass) {
    int i = t + pass * 256;
    if (i < 640) {
      int e = i / 160, hh = (i / 20) % 8, n = i % 20;
      float c[16];
      #pragma unroll
      for (int j = 0; j < 16; ++j) c[j] = 0.f;
      #pragma unroll
      for (int m = 0; m < 20; ++m) {
        const unsigned short* vr = &vs[(e * 20 + m) * 136 + hh * 16];
        bf16x8 va = *(const bf16x8*)vr, vb = *(const bf16x8*)(vr + 8);
        float pv = pm[pass][m];
        #pragma unroll
        for (int j = 0; j < 8; ++j) {
          c[j] = fmaf(pv, bf2f((unsigned short)va[j]), c[j]);
          c[8 + j] = fmaf(pv, bf2f((unsigned short)vb[j]), c[8 + j]);
        }
      }
      bf16x8 c0, c1;
      #pragma unroll
      for (int j = 0; j < 8; ++j) { c0[j] = (short)f2bf(c[j]); c1[j] = (short)f2bf(c[8 + j]); }
      *(bf16x8*)&ctx[(e * 20 + n) * 136 + hh * 16] = c0;
      *(bf16x8*)&ctx[(e * 20 + n) * 136 + hh * 16 + 8] = c1;
    }
  }
  __syncthreads();   // ctx ready; vs fully consumed

  // ---- wo GEMM: M=80 (5 M-tiles, no padding), N=128, K=4 kc ----
  {
    f32x4 acc[5][2];
    #pragma unroll
    for (int mt = 0; mt < 5; ++mt)
      #pragma unroll
      for (int i = 0; i < 2; ++i) acc[mt][i] = (f32x4){0.f, 0.f, 0.f, 0.f};
    #pragma unroll
    for (int kc = 0; kc < 4; ++kc) {
      bf16x8 a[5], b[2];
      #pragma unroll
      for (int mt = 0; mt < 5; ++mt) {
        int g = mt * 16 + l15;
        int e = g / 20, n = g % 20;
        a[mt] = *(const bf16x8*)&ctx[(e * 20 + n) * 136 + kc * 32 + l4 * 8];
      }
      #pragma unroll
      for (int i = 0; i < 2; ++i) {
        int ntg = w * 2 + i;
        b[i] = *(const bf16x8*)&woF[((ntg * 4 + kc) * 64 + l) * 8];
      }
      #pragma unroll
      for (int mt = 0; mt < 5; ++mt)
        #pragma unroll
        for (int i = 0; i < 2; ++i)
          acc[mt][i] = __builtin_amdgcn_mfma_f32_16x16x32_bf16(a[mt], b[i], acc[mt][i], 0, 0, 0);
    }
    // scr (vs region) write — no barrier needed: vs consumed, ctx untouched
    #pragma unroll
    for (int mt = 0; mt < 5; ++mt)
      #pragma unroll
      for (int i = 0; i < 2; ++i) {
        int col = (w * 2 + i) * 16 + l15;
        int gbase = mt * 16 + l4 * 4;
        #pragma unroll
        for (int j = 0; j < 4; ++j)
          scr[(gbase + j) * 136 + col] = f2bf(acc[mt][i][j]);
      }
  }
  __syncthreads();

  // ---- LN1(x + attn_out + bo) -> xr bf16 (80 rows over 4 waves) ----
  for (int r = w; r < 80; r += 4) {
    int e = r / 20, n = r % 20;
    const float* xrow = x + ((size_t)(eb + e) * 20 + n) * 128;
    float v0 = bf2f(scr[r * 136 + l])      + bo[l]      + xrow[l];
    float v1 = bf2f(scr[r * 136 + 64 + l]) + bo[64 + l] + xrow[64 + l];
    float s = v0 + v1, sq = v0 * v0 + v1 * v1;
    #pragma unroll
    for (int off = 32; off > 0; off >>= 1) { s += __shfl_xor(s, off); sq += __shfl_xor(sq, off); }
    float mean = s * (1.f / 128.f);
    float var  = sq * (1.f / 128.f) - mean * mean;
    float inv  = rsqrtf(var + 1e-5f);
    size_t ro = ((size_t)(eb + e) * 20 + n) * 128;
    xr[ro + l]      = f2bf((v0 - mean) * inv * n1w[l] + n1b[l]);
    xr[ro + 64 + l] = f2bf((v1 - mean) * inv * n1w[64 + l] + n1b[64 + l]);
  }
}

// ======================= FFN + LN2 v3 (R6, proven): M=64 rows/block, 2 col phases ================
__global__ __launch_bounds__(256, 3) void ffn_c(
    const unsigned short* __restrict__ xr,
    const unsigned short* __restrict__ w1F, const unsigned short* __restrict__ w2F,
    const float* __restrict__ b1, const float* __restrict__ b2,
    const float* __restrict__ n2w, const float* __restrict__ n2b,
    float* __restrict__ out)
{
  __shared__ __align__(16) char smem[17408 + 33792];
  unsigned short* xrb = (unsigned short*)smem;              // [64][136]
  unsigned short* hh  = (unsigned short*)(smem + 17408);    // [64][264]
  float* sc2          = (float*)(smem + 17408);             // [64][132] aliases hh

  const int t = threadIdx.x;
  const int w = t >> 6, l = t & 63;
  const int l15 = l & 15, l4 = l >> 4;
  const size_t row0 = (size_t)blockIdx.x * 64;

  for (int i = t; i < 1024; i += 256) {
    int r = i >> 4, c8 = i & 15;
    *(bf16x8*)&xrb[r * 136 + c8 * 8] = *(const bf16x8*)&xr[(row0 + r) * 128 + c8 * 8];
  }
  __syncthreads();

  f32x4 acc2[4][2];
  #pragma unroll
  for (int mt = 0; mt < 4; ++mt)
    #pragma unroll
    for (int i = 0; i < 2; ++i) acc2[mt][i] = (f32x4){0.f, 0.f, 0.f, 0.f};

  #pragma unroll
  for (int phase = 0; phase < 2; ++phase) {
    #pragma unroll
    for (int pair = 0; pair < 2; ++pair) {
      f32x4 acc1[4][2];
      #pragma unroll
      for (int mt = 0; mt < 4; ++mt)
        #pragma unroll
        for (int i = 0; i < 2; ++i) acc1[mt][i] = (f32x4){0.f, 0.f, 0.f, 0.f};
      #pragma unroll
      for (int kc = 0; kc < 4; ++kc) {
        bf16x8 a[4];
        #pragma unroll
        for (int mt = 0; mt < 4; ++mt)
          a[mt] = *(const bf16x8*)&xrb[(mt * 16 + l15) * 136 + kc * 32 + l4 * 8];
        #pragma unroll
        for (int i = 0; i < 2; ++i) {
          int ntg = phase * 16 + w * 4 + pair * 2 + i;
          bf16x8 b = *(const bf16x8*)&w1F[((ntg * 4 + kc) * 64 + l) * 8];
          #pragma unroll
          for (int mt = 0; mt < 4; ++mt)
            acc1[mt][i] = __builtin_amdgcn_mfma_f32_16x16x32_bf16(a[mt], b, acc1[mt][i], 0, 0, 0);
        }
      }
      #pragma unroll
      for (int i = 0; i < 2; ++i) {
        int ntg = phase * 16 + w * 4 + pair * 2 + i;
        int lc = (w * 4 + pair * 2 + i) * 16 + l15;
        float b1v = b1[ntg * 16 + l15];
        #pragma unroll
        for (int mt = 0; mt < 4; ++mt)
          #pragma unroll
          for (int j = 0; j < 4; ++j) {
            float v = acc1[mt][i][j] + b1v;
            hh[(mt * 16 + l4 * 4 + j) * 264 + lc] = f2bf(gelu_t(v));
          }
      }
    }
    __syncthreads();

    #pragma unroll
    for (int kk = 0; kk < 8; ++kk) {
      bf16x8 a[4];
      #pragma unroll
      for (int mt = 0; mt < 4; ++mt)
        a[mt] = *(const bf16x8*)&hh[(mt * 16 + l15) * 264 + kk * 32 + l4 * 8];
      #pragma unroll
      for (int i = 0; i < 2; ++i) {
        int ntg = w * 2 + i;
        int kcg = phase * 8 + kk;
        bf16x8 b = *(const bf16x8*)&w2F[((ntg * 16 + kcg) * 64 + l) * 8];
        #pragma unroll
        for (int mt = 0; mt < 4; ++mt)
          acc2[mt][i] = __builtin_amdgcn_mfma_f32_16x16x32_bf16(a[mt], b, acc2[mt][i], 0, 0, 0);
      }
    }
    __syncthreads();
  }

  #pragma unroll
  for (int mt = 0; mt < 4; ++mt)
    #pragma unroll
    for (int i = 0; i < 2; ++i) {
      int col = (w * 2 + i) * 16 + l15;
      int rbase = mt * 16 + l4 * 4;
      #pragma unroll
      for (int j = 0; j < 4; ++j) sc2[(rbase + j) * 132 + col] = acc2[mt][i][j];
    }
  __syncthreads();

  for (int r = w; r < 64; r += 4) {
    float v0 = sc2[r * 132 + l]      + b2[l]      + bf2f(xrb[r * 136 + l]);
    float v1 = sc2[r * 132 + 64 + l] + b2[64 + l] + bf2f(xrb[r * 136 + 64 + l]);
    float s = v0 + v1, sq = v0 * v0 + v1 * v1;
    #pragma unroll
    for (int off = 32; off > 0; off >>= 1) { s += __shfl_xor(s, off); sq += __shfl_xor(sq, off); }
    float mean = s * (1.f / 128.f);
    float var  = sq * (1.f / 128.f) - mean * mean;
    float inv  = rsqrtf(var + 1e-5f);
    out[(row0 + r) * 128 + l]      = (v0 - mean) * inv * n2w[l] + n2b[l];
    out[(row0 + r) * 128 + 64 + l] = (v1 - mean) * inv * n2w[64 + l] + n2b[64 + l];
  }
}

extern "C" void kernel_launch(void* const* d_in, const int* in_sizes, int n_in,
                              void* d_out, int out_size, void* d_ws, size_t ws_size,
                              hipStream_t stream) {
  const float* x     = (const float*)d_in[0];
  const float* wq    = (const float*)d_in[1];
  const float* wk    = (const float*)d_in[2];
  const float* wv    = (const float*)d_in[3];
  const float* lnq_w = (const float*)d_in[4];
  const float* lnq_b = (const float*)d_in[5];
  const float* lnk_w = (const float*)d_in[6];
  const float* lnk_b = (const float*)d_in[7];
  const float* lnv_w = (const float*)d_in[8];
  const float* lnv_b = (const float*)d_in[9];
  const float* rel   = (const float*)d_in[10];
  const float* gb    = (const float*)d_in[11];
  const float* alpha = (const float*)d_in[12];
  const float* wo    = (const float*)d_in[13];
  const float* bo    = (const float*)d_in[14];
  const float* w1    = (const float*)d_in[15];
  const float* b1    = (const float*)d_in[16];
  const float* w2    = (const float*)d_in[17];
  const float* b2    = (const float*)d_in[18];
  const float* n1w   = (const float*)d_in[19];
  const float* n1b   = (const float*)d_in[20];
  const float* n2w   = (const float*)d_in[21];
  const float* n2b   = (const float*)d_in[22];
  float* out = (float*)d_out;

  // ws: WcF | w1F | w2F | woF | biasT (602624 B) | xr (41.9 MB) | qP (41.9 MB). k,v planes in d_out.
  unsigned short* WcF = (unsigned short*)d_ws;     // 147456 us
  unsigned short* w1F = WcF + 147456;              // 65536
  unsigned short* w2F = w1F + 65536;               // 65536
  unsigned short* woF = w2F + 65536;               // 16384
  float* biasT = (float*)(woF + 16384);            // 3200 f32 -> ends at 602624 B
  unsigned short* xr = (unsigned short*)((char*)d_ws + 602624);

  const size_t NEED2 = 602624ULL + 41943040ULL;

  hipLaunchKernelGGL(prep2, dim3(584), dim3(256), 0, stream,
                     wq, wk, wv, w1, w2, wo, rel, gb, alpha, WcF, w1F, w2F, woF, biasT);

  unsigned short* qP = (unsigned short*)((char*)d_ws + NEED2);
  unsigned short* kP = (unsigned short*)d_out;
  unsigned short* vP = kP + (size_t)NROWS * 128;

  hipLaunchKernelGGL(conv_qkv, dim3(NROWS / 128, 3), dim3(256), 0, stream,
                     x, WcF, lnq_w, lnq_b, lnk_w, lnk_b, lnv_w, lnv_b, qP, kP, vP);
  hipLaunchKernelGGL(attn_wo, dim3(NB / 4), dim3(256), 0, stream,
                     x, qP, kP, vP, woF, biasT, bo, n1w, n1b, xr);
  hipLaunchKernelGGL(ffn_c, dim3(NROWS / 64), dim3(256), 0, stream,
                     xr, w1F, w2F, b1, b2, n2w, n2b, out);
}